// Round 1
// 292.655 us; speedup vs baseline: 1.2584x; 1.2584x over previous
//
#include <hip/hip_runtime.h>
#include <hip/hip_bf16.h>

// MetaAdaptiveFusion: B=32, N=2048, H=256, F=8, NH=8, dh=32, 3 meta steps.
// Inputs: fp32 buffers holding bf16-quantized values -> bf16 casts of INPUTS are
// LOSSLESS (docs/u already exploited this in k2/k4; Wv/Wo/meta likewise).
// Computed activations (w, ctx, ho) are hi/lo-split compensated bf16; residual
// carries stay fp32 (registers / MFMA C-operand). Output fp32.
//
// R8: k5_headout (115-135us, MfmaUtil 0, VALUBusy 4%, occupancy 11%, 16 VGPR ->
// pure latency-bound) replaced by MFMA GEMM chain k5_mfma batching 16 b-rows per
// block (grid 16 x 512thr), plus kt_meta which pre-transposes meta to bf16 metaT
// in the dead u-buffer region (u is consumed by k2/k4 before kt_meta runs).
// Fragment layouts follow the verified gfx950 conventions used by k2/k4:
//   A: m=lane&15, k=(lane>>4)*8+j ; B: n=lane&15, same k ; D/C: n=lane&15,
//   m=(lane>>4)*4+reg.
//
// Pipeline: memset(w) ; k1 (qh, u=qh^T Wk/sqrt(dh) bf16, strategy softmax)
//           k2 (MFMA scores -> per-chunk softmax partials pm/pl)
//           k4 (merge partials; MFMA scores recompute; p hi/lo; MFMA p*docs -> w atomics)
//           kt (meta -> bf16 metaT[s][x][r], overlays dead u buffer)
//           k5_mfma (ctx=Wv w+bv; ho=Wo ctx+bo; 3 residual meta steps, all MFMA)
//           k6 (strategy combine)

#define B_ 32
#define N_ 2048
#define H_ 256
#define F_ 8
#define FH_ 64
#define NCH2_ 16   // k2: 16 chunks of 128 docs

typedef unsigned short u16;
typedef __attribute__((ext_vector_type(8))) short bf16x8;   // 8 bf16 (4 VGPRs)
typedef __attribute__((ext_vector_type(4))) float f32x4;
#define MFMA(a, b, c) __builtin_amdgcn_mfma_f32_16x16x32_bf16((a), (b), (c), 0, 0, 0)

__device__ __forceinline__ u16 f2b(float x) {   // fp32 -> bf16 bits, RNE
  unsigned u = __builtin_bit_cast(unsigned, x);
  return (u16)((u + 0x7fffu + ((u >> 16) & 1u)) >> 16);
}
__device__ __forceinline__ float b2f(u16 h) {
  unsigned u = ((unsigned)h) << 16;
  return __builtin_bit_cast(float, u);
}

// ---- ws byte layout (3,687,424 B total, proven safe in R6) ----
static constexpr size_t UB_U     = 0;          // u16 [B][FH][H]    1,048,576
                                               //   (metaT u16[3][256][256]=393,216
                                               //    overlays this after k4)
static constexpr size_t UB_W     = 1048576;    // f32 [B][FH][H]    2,097,152
static constexpr size_t UB_PM    = 3145728;    // f32 [B*FH][16]      131,072
static constexpr size_t UB_PL    = 3276800;    // f32 [B*FH][16]      131,072
static constexpr size_t UB_STRAT = 3424256;    // f32 [B][F]            1,024
static constexpr size_t UB_HO    = 3425280;    // f32 [F][B][H]       262,144

// =============== K1: qh, u, strategy (coalesced wave-per-row dots) ===============
__global__ __launch_bounds__(256) void k1_prep(
    const float* __restrict__ query, const float* __restrict__ ipw,
    const float* __restrict__ ipb, const float* __restrict__ stw,
    const float* __restrict__ stb, u16* __restrict__ u, float* __restrict__ strat)
{
  const int f = blockIdx.x & 7, b = blockIdx.x >> 3;
  const int tid = threadIdx.x, L = tid & 63, w = tid >> 6;
  __shared__ float qh_s[H_];
  __shared__ float logit_s[F_];

  float4 qv = *(const float4*)&query[b * H_ + L * 4];

  // qh rows: wave w handles rows w*64..w*64+63; lane-parallel dot + butterfly
  for (int rr = 0; rr < 64; ++rr) {
    int r = w * 64 + rr;
    float4 a = *(const float4*)&ipw[((size_t)(f * 768) + r) * H_ + L * 4];
    float d = a.x * qv.x + a.y * qv.y + a.z * qv.z + a.w * qv.w;
    #pragma unroll
    for (int m = 32; m; m >>= 1) d += __shfl_xor(d, m, 64);
    if (L == rr) qh_s[r] = d + ipb[f * 768 + r];
  }
  if (f == 0 && w == 0) {  // strategy logits, 8 rows
    for (int rr = 0; rr < 8; ++rr) {
      float4 a = *(const float4*)&stw[rr * H_ + L * 4];
      float d = a.x * qv.x + a.y * qv.y + a.z * qv.z + a.w * qv.w;
      #pragma unroll
      for (int m = 32; m; m >>= 1) d += __shfl_xor(d, m, 64);
      if (L == rr) logit_s[rr] = d + stb[rr];
    }
  }
  __syncthreads();

  // u[b][f*8+h][tid] = (1/sqrt(32)) * sum_d qh[h*32+d] * Wk[h*32+d][tid]  (coalesced)
  const float scale = 0.17677669529663687f;
  for (int h = 0; h < 8; ++h) {
    float acc = 0.f;
    #pragma unroll 8
    for (int d0 = 0; d0 < 32; ++d0) {
      int r = h * 32 + d0;
      acc += qh_s[r] * ipw[((size_t)(f * 768 + 256) + r) * H_ + tid];
    }
    u[((size_t)(b * 64) + f * 8 + h) * H_ + tid] = f2b(acc * scale);
  }
  if (f == 0 && tid == 0) {
    float mx = logit_s[0];
    #pragma unroll
    for (int i = 1; i < F_; ++i) mx = fmaxf(mx, logit_s[i]);
    float s = 0.f, e[F_];
    #pragma unroll
    for (int i = 0; i < F_; ++i) { e[i] = __expf(logit_s[i] - mx); s += e[i]; }
    #pragma unroll
    for (int i = 0; i < F_; ++i) strat[b * F_ + i] = e[i] / s;
  }
}

// =============== K2: MFMA scores -> chunk softmax partials =======================
// grid (16, 32): chunk c = 128 docs. Wave w: rows w*32..+32 (2 M-tiles) x 64 fh.
__global__ __launch_bounds__(256) void k2_stats(
    const float* __restrict__ docs, const float* __restrict__ cw,
    const u16* __restrict__ u, float* __restrict__ pm, float* __restrict__ pl)
{
  const int c = blockIdx.x, b = blockIdx.y;
  const int n0 = c * 128;
  const int tid = threadIdx.x, L = tid & 63, w = tid >> 6;
  const int khi = L >> 4, col = L & 15;

  __shared__ bf16x8 sd8[128 * 9];   // docs chunk [128 n][72 j] bf16 (rows = 9 x b128)
  __shared__ bf16x8 su8[64 * 9];    // u chunk [64 fh][72 j]
  __shared__ float scw[128];
  __shared__ float swred[4][64];
  __shared__ float sbm[64];
  u16* sdu = (u16*)sd8;

  if (tid < 128) scw[tid] = cw[b * N_ + n0 + tid];

  f32x4 acc[2][4];
  #pragma unroll
  for (int t = 0; t < 2; ++t)
    #pragma unroll
    for (int nt = 0; nt < 4; ++nt) acc[t][nt] = (f32x4){0.f, 0.f, 0.f, 0.f};

  for (int j0 = 0; j0 < 256; j0 += 64) {
    if (j0) __syncthreads();
    #pragma unroll
    for (int p = 0; p < 8; ++p) {   // docs [128 n][64 j] fp32 -> bf16
      int idx = tid + 256 * p;
      int n = idx >> 4, jq = (idx & 15) * 4;
      float4 v = *(const float4*)&docs[((size_t)(b * N_) + n0 + n) * H_ + j0 + jq];
      *(ushort4*)&sdu[n * 72 + jq] = make_ushort4(f2b(v.x), f2b(v.y), f2b(v.z), f2b(v.w));
    }
    #pragma unroll
    for (int p = 0; p < 2; ++p) {   // u [64][64]
      int idx = tid + 256 * p;
      int fh = idx >> 3, sub = idx & 7;
      su8[fh * 9 + sub] = *(const bf16x8*)&u[((size_t)(b * 64) + fh) * H_ + j0 + sub * 8];
    }
    __syncthreads();
    #pragma unroll
    for (int kk = 0; kk < 64; kk += 32) {
      bf16x8 a0 = sd8[(w * 32 + col) * 9 + kk / 8 + khi];
      bf16x8 a1 = sd8[(w * 32 + 16 + col) * 9 + kk / 8 + khi];
      #pragma unroll
      for (int nt = 0; nt < 4; ++nt) {
        bf16x8 bb = su8[(nt * 16 + col) * 9 + kk / 8 + khi];
        acc[0][nt] = MFMA(a0, bb, acc[0][nt]);
        acc[1][nt] = MFMA(a1, bb, acc[1][nt]);
      }
    }
  }
  // s = raw * cw ; chunk max / sum-exp per fh
  float cwv[2][4];
  #pragma unroll
  for (int t = 0; t < 2; ++t)
    #pragma unroll
    for (int r = 0; r < 4; ++r) cwv[t][r] = scw[w * 32 + t * 16 + khi * 4 + r];

  float mx[4];
  #pragma unroll
  for (int nt = 0; nt < 4; ++nt) {
    mx[nt] = -3.4e38f;
    #pragma unroll
    for (int t = 0; t < 2; ++t)
      #pragma unroll
      for (int r = 0; r < 4; ++r) {
        float sv = acc[t][nt][r] * cwv[t][r];
        acc[t][nt][r] = sv;
        mx[nt] = fmaxf(mx[nt], sv);
      }
    mx[nt] = fmaxf(mx[nt], __shfl_xor(mx[nt], 16, 64));
    mx[nt] = fmaxf(mx[nt], __shfl_xor(mx[nt], 32, 64));
  }
  if (L < 16) {
    #pragma unroll
    for (int nt = 0; nt < 4; ++nt) swred[w][nt * 16 + L] = mx[nt];
  }
  __syncthreads();
  if (tid < 64)
    sbm[tid] = fmaxf(fmaxf(swred[0][tid], swred[1][tid]),
                     fmaxf(swred[2][tid], swred[3][tid]));
  __syncthreads();
  float ls[4];
  #pragma unroll
  for (int nt = 0; nt < 4; ++nt) {
    float bm = sbm[nt * 16 + col];
    ls[nt] = 0.f;
    #pragma unroll
    for (int t = 0; t < 2; ++t)
      #pragma unroll
      for (int r = 0; r < 4; ++r) ls[nt] += __expf(acc[t][nt][r] - bm);
    ls[nt] += __shfl_xor(ls[nt], 16, 64);
    ls[nt] += __shfl_xor(ls[nt], 32, 64);
  }
  __syncthreads();
  if (L < 16) {
    #pragma unroll
    for (int nt = 0; nt < 4; ++nt) swred[w][nt * 16 + L] = ls[nt];
  }
  __syncthreads();
  if (tid < 64) {
    float bl = swred[0][tid] + swred[1][tid] + swred[2][tid] + swred[3][tid];
    size_t ro = (size_t)(b * 64 + tid) * NCH2_ + c;
    pm[ro] = sbm[tid];
    pl[ro] = bl;
  }
}

// =============== K4: merge partials; scores; p hi/lo; MFMA p*docs -> w ===========
// grid (32, 32): chunk = 64 docs. LDS ~62 KB (fits 64 KB budget, 2 blocks/CU).
__global__ __launch_bounds__(256) void k4_waccum(
    const float* __restrict__ docs, const float* __restrict__ cw,
    const u16* __restrict__ u, const float* __restrict__ pm,
    const float* __restrict__ pl, float* __restrict__ wbuf)
{
  const int c = blockIdx.x, b = blockIdx.y;
  const int n0 = c * 64;
  const int tid = threadIdx.x, L = tid & 63, w = tid >> 6;
  const int khi = L >> 4, col = L & 15;

  __shared__ bf16x8 sdoc8[64 * 33];   // docs [64 n][264 j] bf16
  __shared__ bf16x8 su8[64 * 9];      // u chunk [64 fh][72 j]
  __shared__ bf16x8 ph8[64 * 9];      // p_hi  [64 fh][72 n]
  __shared__ bf16x8 plo8[64 * 9];     // p_lo
  __shared__ float scw[64];
  __shared__ float sm_l[64], sl_l[64];
  u16* sdu  = (u16*)sdoc8;
  u16* phu  = (u16*)ph8;
  u16* plou = (u16*)plo8;

  if (tid < 64) scw[tid] = cw[b * N_ + n0 + tid];
  if (tid >= 64 && tid < 128) {   // fold k3: global m, 1/l per fh from chunk partials
    int fh = tid - 64;
    size_t ro = (size_t)(b * 64 + fh) * NCH2_;
    float m = pm[ro];
    for (int cc = 1; cc < NCH2_; ++cc) m = fmaxf(m, pm[ro + cc]);
    float l = 0.f;
    for (int cc = 0; cc < NCH2_; ++cc) l += pl[ro + cc] * __expf(pm[ro + cc] - m);
    sm_l[fh] = m;
    sl_l[fh] = 1.f / l;
  }
  #pragma unroll
  for (int p = 0; p < 16; ++p) {   // docs [64][256] fp32 -> bf16, coalesced
    int idx = tid + 256 * p;
    int n = idx >> 6, jq = (idx & 63) * 4;
    float4 v = *(const float4*)&docs[((size_t)(b * N_) + n0 + n) * H_ + jq];
    *(ushort4*)&sdu[n * 264 + jq] = make_ushort4(f2b(v.x), f2b(v.y), f2b(v.z), f2b(v.w));
  }
  __syncthreads();

  // phase A: scores for wave's 16 rows (M-tile w) x 64 fh
  f32x4 acc[4];
  #pragma unroll
  for (int nt = 0; nt < 4; ++nt) acc[nt] = (f32x4){0.f, 0.f, 0.f, 0.f};

  for (int j0 = 0; j0 < 256; j0 += 64) {
    #pragma unroll
    for (int p = 0; p < 2; ++p) {
      int idx = tid + 256 * p;
      int fh = idx >> 3, sub = idx & 7;
      su8[fh * 9 + sub] = *(const bf16x8*)&u[((size_t)(b * 64) + fh) * H_ + j0 + sub * 8];
    }
    __syncthreads();
    #pragma unroll
    for (int kk = 0; kk < 64; kk += 32) {
      bf16x8 a0 = sdoc8[(w * 16 + col) * 33 + (j0 + kk) / 8 + khi];
      #pragma unroll
      for (int nt = 0; nt < 4; ++nt) {
        bf16x8 bb = su8[(nt * 16 + col) * 9 + kk / 8 + khi];
        acc[nt] = MFMA(a0, bb, acc[nt]);
      }
    }
    __syncthreads();
  }

  // p = exp(s - m)/l * cw, split hi/lo bf16, transposed into [fh][n]
  #pragma unroll
  for (int nt = 0; nt < 4; ++nt) {
    int fh = nt * 16 + col;
    float m = sm_l[fh], li = sl_l[fh];
    #pragma unroll
    for (int r = 0; r < 4; ++r) {
      int n_loc = w * 16 + khi * 4 + r;
      float cv = scw[n_loc];
      float pv = __expf(acc[nt][r] * cv - m) * li * cv;
      u16 hi = f2b(pv);
      u16 lo = f2b(pv - b2f(hi));
      phu[fh * 72 + n_loc] = hi;
      plou[fh * 72 + n_loc] = lo;
    }
  }
  __syncthreads();

  // phase B: W[fh][j] += sum_n p[fh][n] * docs[n][j]; wave owns j-range w*64..+64
  f32x4 acc2[4][4];
  #pragma unroll
  for (int mt = 0; mt < 4; ++mt)
    #pragma unroll
    for (int nt = 0; nt < 4; ++nt) acc2[mt][nt] = (f32x4){0.f, 0.f, 0.f, 0.f};

  #pragma unroll
  for (int kk = 0; kk < 64; kk += 32) {
    bf16x8 ah[4], al[4];
    #pragma unroll
    for (int mt = 0; mt < 4; ++mt) {
      ah[mt] = ph8[(mt * 16 + col) * 9 + kk / 8 + khi];
      al[mt] = plo8[(mt * 16 + col) * 9 + kk / 8 + khi];
    }
    #pragma unroll
    for (int nt = 0; nt < 4; ++nt) {
      int j = w * 64 + nt * 16 + col;
      bf16x8 bb;
      #pragma unroll
      for (int jj = 0; jj < 8; ++jj)
        bb[jj] = (short)sdu[(kk + khi * 8 + jj) * 264 + j];
      #pragma unroll
      for (int mt = 0; mt < 4; ++mt) {
        acc2[mt][nt] = MFMA(ah[mt], bb, acc2[mt][nt]);
        acc2[mt][nt] = MFMA(al[mt], bb, acc2[mt][nt]);
      }
    }
  }
  #pragma unroll
  for (int mt = 0; mt < 4; ++mt)
    #pragma unroll
    for (int nt = 0; nt < 4; ++nt)
      #pragma unroll
      for (int r = 0; r < 4; ++r) {
        int fh = mt * 16 + khi * 4 + r;
        int j = w * 64 + nt * 16 + col;
        atomicAdd(&wbuf[((size_t)(b * 64) + fh) * H_ + j], acc2[mt][nt][r]);
      }
}

// =============== KT: meta -> bf16 metaT[s][x][r] = meta[s][r][x] =================
// meta is bf16-exact input, so single bf16 (no hi/lo) is lossless. Overlays the
// dead u buffer; must launch after k4 (last reader of u).
__global__ __launch_bounds__(256) void kt_meta(
    const float* __restrict__ meta, u16* __restrict__ metaT)
{
  const int s = blockIdx.x, xg = blockIdx.y;   // s<3, xg<8
  const int x0 = xg * 32;
  const int tid = threadIdx.x;
  __shared__ u16 sT[32 * 264];                 // [32 x][264 r] transposed tile
  #pragma unroll
  for (int p = 0; p < 8; ++p) {                // load 256 r x 32 x, coalesced
    int idx = tid + 256 * p;
    int r = idx >> 3, xq = (idx & 7) * 4;
    float4 v = *(const float4*)&meta[((size_t)(s * 256) + r) * 256 + x0 + xq];
    sT[(xq + 0) * 264 + r] = f2b(v.x);
    sT[(xq + 1) * 264 + r] = f2b(v.y);
    sT[(xq + 2) * 264 + r] = f2b(v.z);
    sT[(xq + 3) * 264 + r] = f2b(v.w);
  }
  __syncthreads();
  #pragma unroll
  for (int p = 0; p < 4; ++p) {                // store rows of metaT, 16B chunks
    int idx = tid + 256 * p;
    int x = idx >> 5, rq = (idx & 31) * 8;
    bf16x8 v = *(bf16x8*)&sT[x * 264 + rq];
    *(bf16x8*)&metaT[((size_t)(s * 256) + x0 + x) * 256 + rq] = v;
  }
}

// =============== K5: MFMA chain ctx -> ho0 -> 3 meta steps =======================
// grid 16 = (f 8) x (b-tile 2 of 16 b), 512 threads (8 waves).
// ctx:  wave w owns NH-head h=w: D[d(2x16 tiles)][b(16)] = Wv_h . w_h^T, K=256
//       panel-staged per 32-k chunk; full K per wave -> no cross-wave reduce.
// ho0:  D[b(16)][x-tile] = ctx . Wo^T + bo ; waves own x-tiles (w*32..+32).
// meta: 3x: ho += ho @ meta[s]; A = ho hi/lo from LDS, B = metaT bf16 (exact)
//       straight from global; residual seed = fp32 accumulator in registers
//       (C-operand geometry identical across steps -> no LDS fp32 round-trip).
// LDS 57,856 B static, regions time-multiplexed:
//   [0,40960)      ctx staging: sWvP[256][40] | sWhiP[128][40] | sWloP[128][40]
//   [0,20480)      ho-phase:    sWo[256][40]
//   [20480,37376)  XB hi/lo [16][264]   (first written in ho0 epilogue)
//   [40960,57856)  XA hi/lo [16][264]   (ctx result)
__global__ __launch_bounds__(512) void k5_mfma(
    const float* __restrict__ ipw, const float* __restrict__ ipb,
    const float* __restrict__ opw, const float* __restrict__ opb,
    const u16* __restrict__ metaT, const float* __restrict__ wbuf,
    float* __restrict__ ho)
{
  const int f = blockIdx.x & 7, b0 = (blockIdx.x >> 3) * 16;
  const int tid = threadIdx.x, L = tid & 63, w = tid >> 6;   // w = wave 0..7
  const int khi = L >> 4, col = L & 15;

  __shared__ char smem[57856];
  u16* sWvP  = (u16*)(smem);             // ctx: [256 (h,d)][40]
  u16* sWhiP = (u16*)(smem + 20480);     // ctx: [128 (h,b)][40]
  u16* sWloP = (u16*)(smem + 30720);
  u16* sWo   = (u16*)(smem);             // ho:  [256 r][40]
  u16* XBh   = (u16*)(smem + 20480);     // [16 b][264 c]
  u16* XBl   = (u16*)(smem + 28928);
  u16* XAh   = (u16*)(smem + 40960);
  u16* XAl   = (u16*)(smem + 49408);

  // ---- ctx: per-ks panels of Wv (all h) and w (all h, hi/lo) ----
  f32x4 cacc0 = (f32x4){0.f, 0.f, 0.f, 0.f};
  f32x4 cacc1 = (f32x4){0.f, 0.f, 0.f, 0.f};
  for (int ks = 0; ks < 8; ++ks) {
    #pragma unroll
    for (int p = 0; p < 4; ++p) {        // Wv panel: 256 rows (h*32+d) x 32 c
      int idx = tid + 512 * p;
      int r = idx >> 3, cq = (idx & 7) * 4;
      float4 v = *(const float4*)&ipw[((size_t)(f * 768 + 512) + r) * 256 + ks * 32 + cq];
      *(ushort4*)&sWvP[r * 40 + cq] = make_ushort4(f2b(v.x), f2b(v.y), f2b(v.z), f2b(v.w));
    }
    #pragma unroll
    for (int p = 0; p < 2; ++p) {        // w panel: 128 rows (h*16+b) x 32 j, hi/lo
      int idx = tid + 512 * p;
      int rr = idx >> 3, cq = (idx & 7) * 4;
      int h = rr >> 4, b = rr & 15;
      float4 v = *(const float4*)&wbuf[((size_t)((b0 + b) * 64) + f * 8 + h) * 256 + ks * 32 + cq];
      u16 hx = f2b(v.x), hy = f2b(v.y), hz = f2b(v.z), hw2 = f2b(v.w);
      *(ushort4*)&sWhiP[rr * 40 + cq] = make_ushort4(hx, hy, hz, hw2);
      *(ushort4*)&sWloP[rr * 40 + cq] = make_ushort4(
          f2b(v.x - b2f(hx)), f2b(v.y - b2f(hy)), f2b(v.z - b2f(hz)), f2b(v.w - b2f(hw2)));
    }
    __syncthreads();
    bf16x8 bh = *(bf16x8*)&sWhiP[(w * 16 + col) * 40 + khi * 8];
    bf16x8 bl = *(bf16x8*)&sWloP[(w * 16 + col) * 40 + khi * 8];
    bf16x8 a0 = *(bf16x8*)&sWvP[(w * 32 + col) * 40 + khi * 8];
    bf16x8 a1 = *(bf16x8*)&sWvP[(w * 32 + 16 + col) * 40 + khi * 8];
    cacc0 = MFMA(a0, bh, cacc0); cacc0 = MFMA(a0, bl, cacc0);
    cacc1 = MFMA(a1, bh, cacc1); cacc1 = MFMA(a1, bl, cacc1);
    __syncthreads();
  }
  // ctx + bv -> XA hi/lo. lane owns (d = mt*16+khi*4+r, b = col) for h = w.
  #pragma unroll
  for (int mt = 0; mt < 2; ++mt) {
    f32x4 cv = mt ? cacc1 : cacc0;
    #pragma unroll
    for (int r = 0; r < 4; ++r) {
      int d = mt * 16 + khi * 4 + r;
      float vv = cv[r] + ipb[f * 768 + 512 + w * 32 + d];
      u16 hi = f2b(vv);
      XAh[col * 264 + w * 32 + d] = hi;
      XAl[col * 264 + w * 32 + d] = f2b(vv - b2f(hi));
    }
  }

  // ---- ho0: D[b][x] = ctx . Wo^T + bo ; waves own x-tiles (w*2+q)*16 ----
  f32x4 hr0, hr1;
  {
    float bo0 = opb[f * 256 + (w * 2 + 0) * 16 + col];
    float bo1 = opb[f * 256 + (w * 2 + 1) * 16 + col];
    hr0 = (f32x4){bo0, bo0, bo0, bo0};
    hr1 = (f32x4){bo1, bo1, bo1, bo1};
  }
  for (int ks = 0; ks < 8; ++ks) {
    #pragma unroll
    for (int p = 0; p < 4; ++p) {        // Wo panel: 256 r x 32 c
      int idx = tid + 512 * p;
      int r = idx >> 3, cq = (idx & 7) * 4;
      float4 v = *(const float4*)&opw[((size_t)(f * 256) + r) * 256 + ks * 32 + cq];
      *(ushort4*)&sWo[r * 40 + cq] = make_ushort4(f2b(v.x), f2b(v.y), f2b(v.z), f2b(v.w));
    }
    __syncthreads();
    bf16x8 ah  = *(bf16x8*)&XAh[col * 264 + ks * 32 + khi * 8];
    bf16x8 al  = *(bf16x8*)&XAl[col * 264 + ks * 32 + khi * 8];
    bf16x8 bw0 = *(bf16x8*)&sWo[((w * 2 + 0) * 16 + col) * 40 + khi * 8];
    bf16x8 bw1 = *(bf16x8*)&sWo[((w * 2 + 1) * 16 + col) * 40 + khi * 8];
    hr0 = MFMA(ah, bw0, hr0); hr0 = MFMA(al, bw0, hr0);
    hr1 = MFMA(ah, bw1, hr1); hr1 = MFMA(al, bw1, hr1);
    __syncthreads();
  }

  // spill ho hi/lo to LDS buffer (Oh/Ol); residual fp32 stays in hr0/hr1
  auto spill = [&](u16* Oh, u16* Ol) {
    #pragma unroll
    for (int q = 0; q < 2; ++q) {
      f32x4 hv = q ? hr1 : hr0;
      int x = (w * 2 + q) * 16 + col;
      #pragma unroll
      for (int r = 0; r < 4; ++r) {
        u16 hi = f2b(hv[r]);
        Oh[(khi * 4 + r) * 264 + x] = hi;
        Ol[(khi * 4 + r) * 264 + x] = f2b(hv[r] - b2f(hi));
      }
    }
  };
  // one meta step: hr += (ho_s) @ meta[s], A = ho_s hi/lo, B = metaT (exact bf16)
  auto meta_mm = [&](const u16* Ah_, const u16* Al_, int s) {
    f32x4 n0 = hr0, n1 = hr1;
    #pragma unroll
    for (int ks = 0; ks < 8; ++ks) {
      bf16x8 ah = *(const bf16x8*)&Ah_[col * 264 + ks * 32 + khi * 8];
      bf16x8 al = *(const bf16x8*)&Al_[col * 264 + ks * 32 + khi * 8];
      const u16* mrow = &metaT[((size_t)(s * 256) + (w * 2) * 16 + col) * 256 + ks * 32 + khi * 8];
      bf16x8 m0 = *(const bf16x8*)mrow;
      bf16x8 m1 = *(const bf16x8*)(mrow + 16 * 256);
      n0 = MFMA(ah, m0, n0); n0 = MFMA(al, m0, n0);
      n1 = MFMA(ah, m1, n1); n1 = MFMA(al, m1, n1);
    }
    hr0 = n0; hr1 = n1;
  };

  spill(XBh, XBl);            // ho0
  __syncthreads();
  meta_mm(XBh, XBl, 0);
  spill(XAh, XAl);
  __syncthreads();
  meta_mm(XAh, XAl, 1);
  spill(XBh, XBl);
  __syncthreads();
  meta_mm(XBh, XBl, 2);

  // final ho (fp32 residual accumulator) -> global [F][B][H]
  #pragma unroll
  for (int q = 0; q < 2; ++q) {
    f32x4 hv = q ? hr1 : hr0;
    int x = (w * 2 + q) * 16 + col;
    #pragma unroll
    for (int r = 0; r < 4; ++r) {
      int b = khi * 4 + r;
      ho[((size_t)(f * B_) + b0 + b) * 256 + x] = hv[r];
    }
  }
}

// =============== K6: strategy combine -> fp32 out ================================
__global__ __launch_bounds__(256) void k6_combine(
    const float* __restrict__ ho, const float* __restrict__ strat,
    float* __restrict__ out)
{
  const int b = blockIdx.x;
  const int tid = threadIdx.x;
  float acc = 0.f;
  #pragma unroll
  for (int f = 0; f < F_; ++f)
    acc += strat[b * F_ + f] * ho[((size_t)(f * B_) + b) * H_ + tid];
  out[b * H_ + tid] = acc;
}

extern "C" void kernel_launch(void* const* d_in, const int* in_sizes, int n_in,
                              void* d_out, int out_size, void* d_ws, size_t ws_size,
                              hipStream_t stream) {
  const float* query = (const float*)d_in[0];
  const float* docs  = (const float*)d_in[1];
  const float* cw    = (const float*)d_in[2];
  // d_in[3] context_history: unused by the reference
  const float* ipw   = (const float*)d_in[4];
  const float* ipb   = (const float*)d_in[5];
  const float* opw   = (const float*)d_in[6];
  const float* opb   = (const float*)d_in[7];
  const float* stw   = (const float*)d_in[8];
  const float* stb   = (const float*)d_in[9];
  const float* meta  = (const float*)d_in[10];
  float* out = (float*)d_out;

  char* base = (char*)d_ws;
  u16*   u     = (u16*)(base + UB_U);
  u16*   metaT = (u16*)(base + UB_U);   // overlays u; written only after k4
  float* wbuf  = (float*)(base + UB_W);
  float* pm    = (float*)(base + UB_PM);
  float* pl    = (float*)(base + UB_PL);
  float* strat = (float*)(base + UB_STRAT);
  float* ho    = (float*)(base + UB_HO);

  hipMemsetAsync(wbuf, 0, (size_t)B_ * FH_ * H_ * sizeof(float), stream);
  k1_prep<<<dim3(F_ * B_), 256, 0, stream>>>(query, ipw, ipb, stw, stb, u, strat);
  k2_stats<<<dim3(NCH2_, B_), 256, 0, stream>>>(docs, cw, u, pm, pl);
  k4_waccum<<<dim3(32, B_), 256, 0, stream>>>(docs, cw, u, pm, pl, wbuf);
  kt_meta<<<dim3(3, 8), 256, 0, stream>>>(meta, metaT);
  k5_mfma<<<dim3(16), 512, 0, stream>>>(ipw, ipb, opw, opb, metaT, wbuf, ho);
  k6_combine<<<dim3(B_), 256, 0, stream>>>(ho, strat, out);
}